// Round 10
// baseline (197.938 us; speedup 1.0000x reference)
//
#include <hip/hip_runtime.h>
#include <hip/hip_bf16.h>
#include <math.h>

#define K_CB 1024
#define D_Z  64
#define MT   32                  // rows per block
#define NTOT 65536
#define NBLK (NTOT / MT)         // 2048

typedef __attribute__((ext_vector_type(8)))  short s16x8;
typedef __attribute__((ext_vector_type(4)))  short s16x4;
typedef __attribute__((ext_vector_type(4)))  float f32x4;
typedef __attribute__((ext_vector_type(16))) float f32x16;

// ws layout (bytes)
#define WS_CB16  0        // [1024][64] bf16
#define WS_CBT16 131072   // [64][1024] bf16
#define WS_NWSQC 262144   // [1024] f32  (-w*||c||^2)
#define WS_PART  266240   // [2048] f32 block partials

__device__ __forceinline__ unsigned short f2b(float f) {
  __hip_bfloat16 h = __float2bfloat16(f);
  return *(unsigned short*)&h;
}
__device__ __forceinline__ unsigned int pk2b(float lo, float hi) {
  float2 v; v.x = lo; v.y = hi;
  __hip_bfloat162 h = __float22bfloat162_rn(v);   // v_cvt_pk_bf16_f32
  return *(unsigned int*)&h;
}
__device__ __forceinline__ float b2f(unsigned short u) {
  return __uint_as_float(((unsigned int)u) << 16);
}

__global__ void vq_prep(const float* __restrict__ cb, const float* __restrict__ lvq,
                        unsigned char* __restrict__ wsb) {
  unsigned short* cb16  = (unsigned short*)(wsb + WS_CB16);
  unsigned short* cbT16 = (unsigned short*)(wsb + WS_CBT16);
  float* nwsqc = (float*)(wsb + WS_NWSQC);
  const float w = 0.5f / fmaxf(1.0f + __expf(lvq[0]), 1e-10f);
  const int tid = threadIdx.x;
  const int k  = blockIdx.x * 16 + (tid >> 4);
  const int d0 = (tid & 15) * 4;
  const f32x4 v = *(const f32x4*)(cb + k * D_Z + d0);
  s16x4 b4;
  #pragma unroll
  for (int i = 0; i < 4; i++) b4[i] = (short)f2b(v[i]);
  *(s16x4*)(cb16 + k * D_Z + d0) = b4;
  #pragma unroll
  for (int i = 0; i < 4; i++) cbT16[(d0 + i) * K_CB + k] = (unsigned short)b4[i];
  float s = v[0]*v[0] + v[1]*v[1] + v[2]*v[2] + v[3]*v[3];
  #pragma unroll
  for (int off = 1; off < 16; off <<= 1) s += __shfl_xor(s, off);
  if ((tid & 15) == 0) nwsqc[k] = -w * s;
}

__global__ __launch_bounds__(512, 2)
void vq_main(const float* __restrict__ x, const float* __restrict__ gum,
             const float* __restrict__ lvq, unsigned char* __restrict__ wsb,
             float* __restrict__ out) {
  __shared__ __align__(16) unsigned short xa[MT * D_Z];   // XOR-swizzled [m][d]
  __shared__ __align__(16) unsigned short es[MT * K_CB];  // XOR-swizzled [m][k]
  __shared__ __align__(16) float stats[8][MT][4];         // m1,s1,A,m2 per wave/row
  __shared__ __align__(16) float s2s[8][MT];
  __shared__ float kldrow[MT];
  __shared__ float wred[8];

  const int tid  = threadIdx.x;
  const int w    = tid >> 6;           // wave 0..7, owns codes [w*128, +128)
  const int lane = tid & 63;
  const int m32  = lane & 31;          // output row (MFMA col)
  const int hi   = lane >> 5;
  const int bid  = blockIdx.x;
  const int blk  = ((bid & 7) << 8) | (bid >> 3);   // bijective XCD remap (2048=8*256)
  const int row0 = blk * MT;
  const int bidx = row0 >> 10;
  const int rem0 = row0 & 1023;
  const int kw0  = w << 7;

  const float wq = 0.5f / fmaxf(1.0f + __expf(lvq[0]), 1e-10f);
  const float w2 = 2.0f * wq;

  const unsigned short* cb16  = (const unsigned short*)(wsb + WS_CB16);
  const unsigned short* cbT16 = (const unsigned short*)(wsb + WS_CBT16);
  const float* nwsqc = (const float*)(wsb + WS_NWSQC);

  // ---- P0: stage x tile [32 rows][64 d] bf16, XOR-swizzled rows ----
  {
    const int m = tid & 31, dg = tid >> 5;   // dg 0..15
    #pragma unroll
    for (int i = 0; i < 4; i++) {
      const int d = dg + 16 * i;
      const float v = x[((bidx * D_Z + d) << 10) + rem0 + m];
      xa[(m * D_Z + d) ^ ((m & 7) << 3)] = f2b(v);
    }
  }
  __syncthreads();

  // ---- GEMM1 (swapped, 32x32x16): D[code][m], wave codes kw0..+128 ----
  f32x16 acc[4];
  #pragma unroll
  for (int t = 0; t < 4; t++)
    #pragma unroll
    for (int r = 0; r < 16; r++) acc[t][r] = 0.f;
  {
    s16x8 bx[4];
    #pragma unroll
    for (int kb = 0; kb < 4; kb++) {
      const int byteoff = (m32 * 128 + kb * 32 + hi * 16) ^ ((m32 & 7) << 4);
      bx[kb] = *(const s16x8*)((const unsigned char*)xa + byteoff);
    }
    __builtin_amdgcn_s_setprio(1);
    #pragma unroll
    for (int t = 0; t < 4; t++) {
      const unsigned short* ap = cb16 + (kw0 + t * 32 + m32) * D_Z + hi * 8;
      #pragma unroll
      for (int kb = 0; kb < 4; kb++) {
        const s16x8 a = *(const s16x8*)(ap + kb * 16);
        acc[t] = __builtin_amdgcn_mfma_f32_32x32x16_bf16(a, bx[kb], acc[t], 0, 0, 0);
      }
    }
    __builtin_amdgcn_s_setprio(0);
  }

  // ---- logits: acc = w2*cross + (-w*||c||^2); per-wave row max m1 ----
  float m1 = -3.4e38f;
  #pragma unroll
  for (int t = 0; t < 4; t++) {
    #pragma unroll
    for (int q = 0; q < 4; q++) {
      const f32x4 nw = *(const f32x4*)(nwsqc + kw0 + t * 32 + q * 8 + hi * 4);
      #pragma unroll
      for (int i = 0; i < 4; i++) {
        acc[t][q * 4 + i] = fmaf(w2, acc[t][q * 4 + i], nw[i]);
        m1 = fmaxf(m1, acc[t][q * 4 + i]);
      }
    }
  }
  m1 = fmaxf(m1, __shfl_xor(m1, 32));

  // ---- issue gumbel batch A (tiles 0,1); latency hidden under s1/A pass ----
  const float* gp = gum + ((size_t)(row0 + m32) << 10) + kw0 + hi * 4;
  f32x4 gA[8];
  #pragma unroll
  for (int u = 0; u < 8; u++)
    gA[u] = *(const f32x4*)(gp + (u >> 2) * 32 + (u & 3) * 8);

  // ---- s1 / A pass ----
  float s1 = 0.f, Aa = 0.f;
  #pragma unroll
  for (int t = 0; t < 4; t++) {
    #pragma unroll
    for (int r = 0; r < 16; r++) {
      const float u = acc[t][r] - m1;
      const float e = __expf(u);
      s1 += e;
      Aa = fmaf(u, e, Aa);
    }
  }
  s1 += __shfl_xor(s1, 32);
  Aa += __shfl_xor(Aa, 32);

  // ---- z = 2*(logit+g): tiles 0,1; issue batch B; tiles 2,3; per-wave m2 ----
  float m2 = -3.4e38f;
  #pragma unroll
  for (int u = 0; u < 8; u++) {
    const int t = u >> 2, q = u & 3;
    #pragma unroll
    for (int i = 0; i < 4; i++) {
      const float z = 2.0f * (acc[t][q * 4 + i] + gA[u][i]);
      acc[t][q * 4 + i] = z;
      m2 = fmaxf(m2, z);
    }
  }
  f32x4 gB[8];
  #pragma unroll
  for (int u = 0; u < 8; u++)
    gB[u] = *(const f32x4*)(gp + 64 + (u >> 2) * 32 + (u & 3) * 8);
  #pragma unroll
  for (int u = 0; u < 8; u++) {
    const int t = 2 + (u >> 2), q = u & 3;
    #pragma unroll
    for (int i = 0; i < 4; i++) {
      const float z = 2.0f * (acc[t][q * 4 + i] + gB[u][i]);
      acc[t][q * 4 + i] = z;
      m2 = fmaxf(m2, z);
    }
  }
  m2 = fmaxf(m2, __shfl_xor(m2, 32));
  if (hi == 0) {
    f32x4 st = {m1, s1, Aa, m2};
    *(f32x4*)&stats[w][m32][0] = st;
  }
  __syncthreads();

  // ---- cross-wave: global row max M2; wave 0 computes kld_discrete rows ----
  float M2 = -3.4e38f;
  {
    f32x4 st[8];
    #pragma unroll
    for (int q = 0; q < 8; q++) {
      st[q] = *(const f32x4*)&stats[q][m32][0];
      M2 = fmaxf(M2, st[q][3]);
    }
    if (w == 0) {
      float M1 = -3.4e38f;
      #pragma unroll
      for (int q = 0; q < 8; q++) M1 = fmaxf(M1, st[q][0]);
      float s1g = 0.f, Ag = 0.f;
      #pragma unroll
      for (int q = 0; q < 8; q++) {
        const float dm = st[q][0] - M1;
        const float c  = __expf(dm);
        s1g += c * st[q][1];
        Ag = fmaf(c, fmaf(dm, st[q][1], st[q][2]), Ag);
      }
      if (hi == 0) kldrow[m32] = Ag / s1g - __logf(s1g);
    }
  }

  // ---- encode e = exp(z - M2) (row-global baseline), cvt_pk bf16 -> es ----
  float s2 = 0.f;
  #pragma unroll
  for (int t = 0; t < 4; t++) {
    #pragma unroll
    for (int q = 0; q < 4; q++) {
      float e[4];
      #pragma unroll
      for (int i = 0; i < 4; i++) {
        e[i] = __expf(acc[t][q * 4 + i] - M2);
        s2 += e[i];
      }
      const unsigned int p0 = pk2b(e[0], e[1]);
      const unsigned int p1 = pk2b(e[2], e[3]);
      const unsigned long long pk = (unsigned long long)p0 | ((unsigned long long)p1 << 32);
      const int byteoff = (m32 * 2048 + (kw0 + t * 32 + q * 8 + hi * 4) * 2) ^ ((m32 & 7) << 4);
      *(unsigned long long*)((unsigned char*)es + byteoff) = pk;
    }
  }
  s2 += __shfl_xor(s2, 32);
  if (hi == 0) s2s[w][m32] = s2;
  __syncthreads();

  // ---- GEMM2 (swapped, 16x16x32): wave -> tile (d-block w>>1, m-block w&1) ----
  const int m16 = lane & 15, g16 = lane >> 4;
  const int db = w >> 1, mb = w & 1;
  const int mrow = mb * 16 + m16;
  float s2g = 0.f;
  #pragma unroll
  for (int q = 0; q < 8; q++) s2g += s2s[q][mrow];
  const float inv2 = 1.0f / s2g;

  f32x4 qacc = (f32x4){0.f, 0.f, 0.f, 0.f};
  {
    const unsigned short* a2p = cbT16 + (db * 16 + m16) * K_CB + g16 * 8;
    const unsigned char* esb = (const unsigned char*)es;
    __builtin_amdgcn_s_setprio(1);
    #pragma unroll
    for (int kc = 0; kc < 32; kc++) {
      const s16x8 a2 = *(const s16x8*)(a2p + kc * 32);
      const int byteoff = (mrow * 2048 + kc * 64 + g16 * 16) ^ ((m16 & 7) << 4);
      const s16x8 b2 = *(const s16x8*)(esb + byteoff);
      qacc = __builtin_amdgcn_mfma_f32_16x16x32_bf16(a2, b2, qacc, 0, 0, 0);
    }
    __builtin_amdgcn_s_setprio(0);
  }

  // ---- epilogue: normalize, write, kld_continuous (x from LDS, bf16 ok) ----
  float kca = 0.f;
  {
    const int d0 = db * 16 + g16 * 4;
    const s16x4 xb = *(const s16x4*)&xa[(mrow * D_Z + d0) ^ ((mrow & 7) << 3)];
    #pragma unroll
    for (int r = 0; r < 4; r++) {
      const int d = d0 + r;
      const int off = ((bidx * D_Z + d) << 10) + rem0 + mrow;
      const float qv = qacc[r] * inv2;
      out[off] = qv;
      const float dx = b2f((unsigned short)xb[r]) - qv;
      kca = fmaf(dx, dx, kca);
    }
  }
  #pragma unroll
  for (int off = 1; off < 64; off <<= 1) kca += __shfl_xor(kca, off);
  if (lane == 0) wred[w] = kca;
  __syncthreads();
  if (tid == 0) {
    float tot = 0.f;
    #pragma unroll
    for (int q = 0; q < 8; q++) tot += wred[q];
    tot *= wq;
    #pragma unroll
    for (int i = 0; i < MT; i++) tot += kldrow[i];
    ((float*)(wsb + WS_PART))[blk] = tot;
  }
}

__global__ void vq_reduce(const unsigned char* __restrict__ wsb, float* __restrict__ out) {
  __shared__ float red[256];
  const float* part = (const float*)(wsb + WS_PART);
  const int t = threadIdx.x;
  float s = 0.f;
  for (int i = t; i < NBLK; i += 256) s += part[i];
  red[t] = s;
  __syncthreads();
  for (int st = 128; st > 0; st >>= 1) {
    if (t < st) red[t] += red[t + st];
    __syncthreads();
  }
  if (t == 0) out[NTOT * D_Z] = red[0] * (1.0f / 64.0f);
}

extern "C" void kernel_launch(void* const* d_in, const int* in_sizes, int n_in,
                              void* d_out, int out_size, void* d_ws, size_t ws_size,
                              hipStream_t stream) {
  const float* x   = (const float*)d_in[0];
  const float* cb  = (const float*)d_in[1];
  const float* lvq = (const float*)d_in[2];
  const float* gum = (const float*)d_in[3];
  float* out = (float*)d_out;
  unsigned char* wsb = (unsigned char*)d_ws;

  hipLaunchKernelGGL(vq_prep,   dim3(64),   dim3(256), 0, stream, cb, lvq, wsb);
  hipLaunchKernelGGL(vq_main,   dim3(NBLK), dim3(512), 0, stream, x, gum, lvq, wsb, out);
  hipLaunchKernelGGL(vq_reduce, dim3(1),    dim3(256), 0, stream, wsb, out);
}

// Round 11
// 183.170 us; speedup vs baseline: 1.0806x; 1.0806x over previous
//
#include <hip/hip_runtime.h>
#include <hip/hip_bf16.h>
#include <math.h>

#define K_CB 1024
#define D_Z  64
#define MT   16
#define NTOT 65536
#define NBLK (NTOT / MT)   // 4096

typedef __attribute__((ext_vector_type(8))) short s16x8;
typedef __attribute__((ext_vector_type(4))) short s16x4;
typedef __attribute__((ext_vector_type(4))) float f32x4;

// ws layout (bytes)
#define WS_CB16  0        // [1024][64] bf16
#define WS_CBT2  131072   // [64][1024] bf16, columns PERMUTED to GEMM2 slot order
#define WS_NWSQC 262144   // [1024] f32 (-w*||c||^2)
#define WS_PART  266240   // [4096] f32 block partials

__device__ __forceinline__ unsigned short f2b(float f) {
  unsigned int u = __float_as_uint(f);
  u += 0x7fffu + ((u >> 16) & 1u);
  return (unsigned short)(u >> 16);
}
__device__ __forceinline__ unsigned int pk2b(float lo, float hi) {
  float2 v; v.x = lo; v.y = hi;
  __hip_bfloat162 h = __float22bfloat162_rn(v);   // v_cvt_pk_bf16_f32
  return *(unsigned int*)&h;
}
__device__ __forceinline__ float b2f(unsigned short u) {
  return __uint_as_float(((unsigned int)u) << 16);
}

// GEMM2 slot permutation: wave-local code r (0..255) -> column slot.
// slot = ks*32 + g*8 + jb*4 + jl  where r = ks*32 + jb*16 + g*4 + jl.
// This makes the B-fragment for step ks consist of each lane's OWN
// D-fragment values from GEMM1 (no cross-lane movement needed).
__device__ __forceinline__ int colof(int k) {
  const int r = k & 255;
  return (k & ~255) | ((r >> 5) << 5) | (((r >> 2) & 3) << 3)
       | (((r >> 4) & 1) << 2) | (r & 3);
}

__global__ void vq_prep(const float* __restrict__ cb, const float* __restrict__ lvq,
                        unsigned char* __restrict__ wsb) {
  unsigned short* cb16 = (unsigned short*)(wsb + WS_CB16);
  unsigned short* cbT2 = (unsigned short*)(wsb + WS_CBT2);
  float* nwsqc = (float*)(wsb + WS_NWSQC);
  const float w = 0.5f / fmaxf(1.0f + __expf(lvq[0]), 1e-10f);
  const int tid = threadIdx.x;
  const int k  = blockIdx.x * 16 + (tid >> 4);
  const int d0 = (tid & 15) * 4;
  const f32x4 v = *(const f32x4*)(cb + k * D_Z + d0);
  s16x4 b4;
  #pragma unroll
  for (int i = 0; i < 4; i++) b4[i] = (short)f2b(v[i]);
  *(s16x4*)(cb16 + k * D_Z + d0) = b4;
  const int col = colof(k);
  #pragma unroll
  for (int i = 0; i < 4; i++) cbT2[(d0 + i) * K_CB + col] = (unsigned short)b4[i];
  float s = v[0]*v[0] + v[1]*v[1] + v[2]*v[2] + v[3]*v[3];
  #pragma unroll
  for (int off = 1; off < 16; off <<= 1) s += __shfl_xor(s, off);
  if ((tid & 15) == 0) nwsqc[k] = -w * s;
}

__global__ __launch_bounds__(256, 3)
void vq_main(const float* __restrict__ x, const float* __restrict__ gum,
             const float* __restrict__ lvq, unsigned char* __restrict__ wsb,
             float* __restrict__ out) {
  // LDS ~20KB -> many blocks allowed; residency is register-bound (~3 blocks/CU)
  __shared__ __align__(16) unsigned short xa[MT * D_Z];   // 2KB frag-linear
  __shared__ __align__(16) float qpart[4][MT][D_Z];       // 16KB f32 partials (swizzled)
  __shared__ __align__(16) float st4[4][MT][4];           // m1,s1,Aa,m2
  __shared__ __align__(16) float s2s[4][MT];
  __shared__ float wred[4];

  const int tid  = threadIdx.x;
  const int w    = tid >> 6;            // wave 0..3, owns codes [w*256, +256)
  const int lane = tid & 63;
  const int m16  = lane & 15;           // pixel row (MFMA col)
  const int g    = lane >> 4;           // k-group
  const int bid  = blockIdx.x;
  const int blk  = ((bid & 7) << 9) | (bid >> 3);   // bijective XCD remap (4096=8*512)
  const int row0 = blk * MT;
  const int bidx = row0 >> 10;
  const int rem0 = row0 & 1023;
  const int kw0  = w << 8;

  const float wq = 0.5f / fmaxf(1.0f + __expf(lvq[0]), 1e-10f);
  const float w2 = 2.0f * wq;

  const unsigned short* cb16 = (const unsigned short*)(wsb + WS_CB16);
  const unsigned short* cbT2 = (const unsigned short*)(wsb + WS_CBT2);
  const float* nwsqc = (const float*)(wsb + WS_NWSQC);

  // ---- P0: stage x tile, MFMA-frag-linear bf16 layout ----
  {
    const int m = tid & 15, db = tid >> 4;
    #pragma unroll
    for (int i = 0; i < 4; i++) {
      const int d = db + 16 * i;
      const float v = x[((bidx * D_Z + d) << 10) + rem0 + m];
      xa[(d >> 5) * 512 + ((d >> 3) & 3) * 128 + m * 8 + (d & 7)] = f2b(v);
    }
  }
  __syncthreads();

  // ---- GEMM1 (swapped, 16x16x32): D[code][m], 16 tiles of 16 codes ----
  f32x4 acc[16];
  #pragma unroll
  for (int t = 0; t < 16; t++) acc[t] = (f32x4){0.f, 0.f, 0.f, 0.f};
  {
    const s16x8 xb0 = *(const s16x8*)(xa + g * 128 + m16 * 8);
    const s16x8 xb1 = *(const s16x8*)(xa + 512 + g * 128 + m16 * 8);
    const unsigned short* ap = cb16 + (kw0 + m16) * D_Z + g * 8;
    #pragma unroll
    for (int t = 0; t < 16; t++) {
      const s16x8 a0 = *(const s16x8*)(ap + t * 1024);
      const s16x8 a1 = *(const s16x8*)(ap + t * 1024 + 32);
      acc[t] = __builtin_amdgcn_mfma_f32_16x16x32_bf16(a0, xb0, acc[t], 0, 0, 0);
      acc[t] = __builtin_amdgcn_mfma_f32_16x16x32_bf16(a1, xb1, acc[t], 0, 0, 0);
    }
  }

  // ---- logits + per-wave row max m1 (lane's code = kw0 + t*16 + g*4 + i) ----
  float m1 = -3.4e38f;
  #pragma unroll
  for (int t = 0; t < 16; t++) {
    const f32x4 nw = *(const f32x4*)(nwsqc + kw0 + t * 16 + g * 4);
    #pragma unroll
    for (int i = 0; i < 4; i++) {
      acc[t][i] = fmaf(w2, acc[t][i], nw[i]);
      m1 = fmaxf(m1, acc[t][i]);
    }
  }
  m1 = fmaxf(m1, __shfl_xor(m1, 16));
  m1 = fmaxf(m1, __shfl_xor(m1, 32));

  // ---- issue gumbel batch A (tiles 0..7); hidden under s1/A pass ----
  const float* gp = gum + ((size_t)(row0 + m16) << 10) + kw0 + g * 4;
  f32x4 gA[8];
  #pragma unroll
  for (int u = 0; u < 8; u++) gA[u] = *(const f32x4*)(gp + u * 16);

  // ---- s1 / Aa pass ----
  float s1 = 0.f, Aa = 0.f;
  #pragma unroll
  for (int t = 0; t < 16; t++) {
    #pragma unroll
    for (int i = 0; i < 4; i++) {
      const float u = acc[t][i] - m1;
      const float e = __expf(u);
      s1 += e;
      Aa = fmaf(u, e, Aa);
    }
  }
  s1 += __shfl_xor(s1, 16); s1 += __shfl_xor(s1, 32);
  Aa += __shfl_xor(Aa, 16); Aa += __shfl_xor(Aa, 32);

  // ---- z = 2*(logit+g): tiles 0..7; issue batch B; tiles 8..15; wave m2 ----
  float m2 = -3.4e38f;
  #pragma unroll
  for (int u = 0; u < 8; u++) {
    #pragma unroll
    for (int i = 0; i < 4; i++) {
      const float z = 2.0f * (acc[u][i] + gA[u][i]);
      acc[u][i] = z;
      m2 = fmaxf(m2, z);
    }
  }
  f32x4 gB[8];
  #pragma unroll
  for (int u = 0; u < 8; u++) gB[u] = *(const f32x4*)(gp + (8 + u) * 16);
  #pragma unroll
  for (int u = 0; u < 8; u++) {
    #pragma unroll
    for (int i = 0; i < 4; i++) {
      const float z = 2.0f * (acc[8 + u][i] + gB[u][i]);
      acc[8 + u][i] = z;
      m2 = fmaxf(m2, z);
    }
  }
  m2 = fmaxf(m2, __shfl_xor(m2, 16));
  m2 = fmaxf(m2, __shfl_xor(m2, 32));
  if (g == 0) {
    f32x4 st = {m1, s1, Aa, m2};
    *(f32x4*)&st4[w][m16][0] = st;
  }

  // ---- encode e' = exp(z - m2_wave) IN-REGISTER (no cross-wave wait) ----
  float s2 = 0.f;
  #pragma unroll
  for (int t = 0; t < 16; t++) {
    #pragma unroll
    for (int i = 0; i < 4; i++) {
      const float e = __expf(acc[t][i] - m2);
      acc[t][i] = e;
      s2 += e;
    }
  }
  s2 += __shfl_xor(s2, 16); s2 += __shfl_xor(s2, 32);
  if (g == 0) s2s[w][m16] = s2;

  // ---- pack B-fragments from OWN values (cbT2 permutation absorbs layout) ----
  s16x8 fr[8];
  #pragma unroll
  for (int ks = 0; ks < 8; ks++) {
    unsigned int q0 = pk2b(acc[2*ks][0],   acc[2*ks][1]);
    unsigned int q1 = pk2b(acc[2*ks][2],   acc[2*ks][3]);
    unsigned int q2 = pk2b(acc[2*ks+1][0], acc[2*ks+1][1]);
    unsigned int q3 = pk2b(acc[2*ks+1][2], acc[2*ks+1][3]);
    unsigned int wv4[4] = {q0, q1, q2, q3};
    fr[ks] = *(s16x8*)wv4;
  }

  // ---- GEMM2 partial (in-register): Qp_w[d][m] over wave's 256 codes ----
  f32x4 qp[4];
  #pragma unroll
  for (int dt = 0; dt < 4; dt++) qp[dt] = (f32x4){0.f, 0.f, 0.f, 0.f};
  {
    const unsigned short* a2base = cbT2 + m16 * K_CB + kw0 + g * 8;
    #pragma unroll
    for (int ks = 0; ks < 8; ks++) {
      #pragma unroll
      for (int dt = 0; dt < 4; dt++) {
        const s16x8 a2 = *(const s16x8*)(a2base + dt * 16 * K_CB + ks * 32);
        qp[dt] = __builtin_amdgcn_mfma_f32_16x16x32_bf16(a2, fr[ks], qp[dt], 0, 0, 0);
      }
    }
  }

  // ---- write f32 partials (swizzled) ----
  {
    unsigned char* qb = (unsigned char*)qpart;
    #pragma unroll
    for (int dt = 0; dt < 4; dt++) {
      const int d0 = dt * 16 + g * 4;
      const int addr = ((w * 16 + m16) * 256 + d0 * 4) ^ ((m16 & 7) << 4);
      *(f32x4*)(qb + addr) = qp[dt];
    }
  }
  __syncthreads();

  // ---- merge: wave w owns d in [16w, 16w+16) for all 16 rows ----
  {
    const int m = lane & 15, dgrp = lane >> 4;
    const int d0 = w * 16 + dgrp * 4;
    f32x4 sq[4];
    #pragma unroll
    for (int q = 0; q < 4; q++) sq[q] = *(const f32x4*)&st4[q][m][0];
    float M2 = fmaxf(fmaxf(sq[0][3], sq[1][3]), fmaxf(sq[2][3], sq[3][3]));
    float cw[4], s2g = 0.f;
    #pragma unroll
    for (int q = 0; q < 4; q++) {
      cw[q] = __expf(sq[q][3] - M2);
      s2g = fmaf(cw[q], s2s[q][m], s2g);
    }
    const float inv2 = 1.0f / s2g;
    f32x4 osum = (f32x4){0.f, 0.f, 0.f, 0.f};
    const unsigned char* qb = (const unsigned char*)qpart;
    #pragma unroll
    for (int q = 0; q < 4; q++) {
      const int addr = ((q * 16 + m) * 256 + d0 * 4) ^ ((m & 7) << 4);
      const f32x4 p = *(const f32x4*)(qb + addr);
      #pragma unroll
      for (int i = 0; i < 4; i++) osum[i] = fmaf(cw[q], p[i], osum[i]);
    }
    // output + kld_continuous (x from LDS bf16)
    float kca = 0.f;
    const s16x4 xb = *(const s16x4*)&xa[(d0 >> 5) * 512 + ((d0 >> 3) & 3) * 128 + m * 8 + (d0 & 7)];
    #pragma unroll
    for (int r = 0; r < 4; r++) {
      const int d = d0 + r;
      const float qv = osum[r] * inv2;
      out[((bidx * D_Z + d) << 10) + rem0 + m] = qv;
      const float dx = b2f((unsigned short)xb[r]) - qv;
      kca = fmaf(dx, dx, kca);
    }
    #pragma unroll
    for (int off = 1; off < 64; off <<= 1) kca += __shfl_xor(kca, off);
    if (lane == 0) wred[w] = kca;

    // kld_discrete: wave 0, dgrp==0 lanes (one per row m)
    float kld = 0.f;
    if (w == 0) {
      float M1 = fmaxf(fmaxf(sq[0][0], sq[1][0]), fmaxf(sq[2][0], sq[3][0]));
      float s1g = 0.f, Ag = 0.f;
      #pragma unroll
      for (int q = 0; q < 4; q++) {
        const float dm = sq[q][0] - M1;
        const float c  = __expf(dm);
        s1g += c * sq[q][1];
        Ag = fmaf(c, fmaf(dm, sq[q][1], sq[q][2]), Ag);
      }
      kld = (dgrp == 0) ? (Ag / s1g - __logf(s1g)) : 0.f;
      #pragma unroll
      for (int off = 1; off < 64; off <<= 1) kld += __shfl_xor(kld, off);
    }
    __syncthreads();
    if (tid == 0) {
      const float tot = wq * (wred[0] + wred[1] + wred[2] + wred[3]) + kld;
      ((float*)(wsb + WS_PART))[blk] = tot;
    }
  }
}

__global__ void vq_reduce(const unsigned char* __restrict__ wsb, float* __restrict__ out) {
  __shared__ float red[256];
  const float* part = (const float*)(wsb + WS_PART);
  const int t = threadIdx.x;
  float s = 0.f;
  for (int i = t; i < NBLK; i += 256) s += part[i];
  red[t] = s;
  __syncthreads();
  for (int st = 128; st > 0; st >>= 1) {
    if (t < st) red[t] += red[t + st];
    __syncthreads();
  }
  if (t == 0) out[NTOT * D_Z] = red[0] * (1.0f / 64.0f);
}

extern "C" void kernel_launch(void* const* d_in, const int* in_sizes, int n_in,
                              void* d_out, int out_size, void* d_ws, size_t ws_size,
                              hipStream_t stream) {
  const float* x   = (const float*)d_in[0];
  const float* cb  = (const float*)d_in[1];
  const float* lvq = (const float*)d_in[2];
  const float* gum = (const float*)d_in[3];
  float* out = (float*)d_out;
  unsigned char* wsb = (unsigned char*)d_ws;

  hipLaunchKernelGGL(vq_prep,   dim3(64),   dim3(256), 0, stream, cb, lvq, wsb);
  hipLaunchKernelGGL(vq_main,   dim3(NBLK), dim3(256), 0, stream, x, gum, lvq, wsb, out);
  hipLaunchKernelGGL(vq_reduce, dim3(1),    dim3(256), 0, stream, wsb, out);
}